// Round 8
// baseline (130.901 us; speedup 1.0000x reference)
//
#include <hip/hip_runtime.h>
#include <cmath>

#define NN 64
#define CC 96
#define TT 128
#define VV 25
#define SS 3
#define TB 4
#define NTB (TT/TB)          /* 32 */
#define ROWS (TB*VV)         /* 100 */

#define XFP 104              /* xf [c][i-compact] staging pitch */
#define X3P 104              /* xT32 row pitch (128 rows = dt*32+v) */
#define QKP 200              /* qk row pitch (128 rows = i') */
#define YP  104              /* yL row pitch */
#define WLP 104              /* wL row pitch */

typedef __attribute__((ext_vector_type(8))) __bf16 bf16x8;
typedef __attribute__((ext_vector_type(4))) float f32x4;

#define MFMA16(a,b,c) __builtin_amdgcn_mfma_f32_16x16x32_bf16((a),(b),(c),0,0,0)

__constant__ int JP[25] = {0,0,1,1,2,2,2,3,4,4,4,5,6,6,7,7,8,8,9,9,0,3,3,5,5};
__constant__ int JB[25] = {4,4,4,4,0,0,0,0,1,1,1,1,2,2,2,2,3,3,3,3,4,0,0,1,1};

__device__ inline unsigned short f2b(float f) {
  unsigned int u = __float_as_uint(f);
  u += 0x7fffu + ((u >> 16) & 1u);
  return (unsigned short)(u >> 16);
}
__device__ inline bf16x8 ldbf8(const unsigned short* p) {
  union { uint4 u; bf16x8 b; } z;
  z.u = *(const uint4*)p;
  return z.b;
}
__device__ inline f32x4 fz() {
  f32x4 z; z[0] = 0.f; z[1] = 0.f; z[2] = 0.f; z[3] = 0.f; return z;
}

// ---------------------------------------------------------------------------
// k0: weights -> bf16 in ws; BN scale/shift precompute
// ---------------------------------------------------------------------------
__global__ __launch_bounds__(256) void k0(
    const float* __restrict__ w_in, const float* __restrict__ w_ff,
    const float* __restrict__ b_ff, const float* __restrict__ gam,
    const float* __restrict__ bet, const float* __restrict__ mea,
    const float* __restrict__ var,
    unsigned short* __restrict__ wbin, unsigned short* __restrict__ wbff,
    float* __restrict__ scsh)
{
  int i = blockIdx.x * 256 + threadIdx.x;
  if (i < 288 * 96) wbin[i] = f2b(w_in[i]);
  if (i < 96 * 96)  wbff[i] = f2b(w_ff[i]);
  if (i < 96) {
    float sc = gam[i] * rsqrtf(var[i] + 1e-5f);
    scsh[i]      = sc;
    scsh[96 + i] = (b_ff[i] - mea[i]) * sc + bet[i];
  }
}

// ---------------------------------------------------------------------------
// k1: per (n, tb): QK GEMM -> Gram partials ; VAL GEMM -> val_ws.
// xT32 rows = dt*32+v (pads zeroed) so all downstream writes are aligned.
// LDS: xT32 26624 + qk 51200 + bL 768 = 78592 B -> 2 blocks/CU.
// ---------------------------------------------------------------------------
__global__ __launch_bounds__(256, 2) void k1(
    const float* __restrict__ x, const unsigned short* __restrict__ wbin,
    const float* __restrict__ b_in, float* __restrict__ partG,
    unsigned short* __restrict__ val_ws)
{
  __shared__ __align__(16) unsigned short xT32[128 * X3P];  // 26624 B
  __shared__ __align__(16) unsigned short qk[128 * QKP];    // 51200 B
  __shared__ float bL[192];
  unsigned short* xf   = qk;   // staging alias (9984 u16)
  unsigned short* valL = qk;   // VAL output alias [96][128] (12288 u16)

  const int tid  = threadIdx.x;
  const int wid  = tid >> 6, lane = tid & 63;
  const int lrow = lane & 15;
  const int lk8  = (lane >> 4) << 3;
  const int ldr4 = (lane >> 4) << 2;
  const int tb = blockIdx.x & (NTB - 1);
  const int n  = blockIdx.x >> 5;
  const int t0 = tb * TB;

  // ---- phase 1: coalesced x load -> xf[c][i-compact]; zero xT32 pad rows
  const float* xb = x + (size_t)n * CC * TT * VV + (size_t)t0 * VV;
  for (int e = tid; e < CC * (ROWS / 4); e += 256) {
    int i4 = e % (ROWS / 4), c = e / (ROWS / 4);
    float4 v = *(const float4*)&xb[(size_t)c * (TT * VV) + i4 * 4];
    ushort4 h;
    h.x = f2b(v.x); h.y = f2b(v.y); h.z = f2b(v.z); h.w = f2b(v.w);
    *(ushort4*)&xf[c * XFP + i4 * 4] = h;
  }
  for (int e = tid; e < 28 * 13; e += 256) {
    int pr = e / 13, q = e % 13;
    int row = (pr / 7) * 32 + 25 + (pr % 7);
    uint4 z; z.x = 0u; z.y = 0u; z.z = 0u; z.w = 0u;
    *(uint4*)&xT32[row * X3P + q * 8] = z;
  }
  if (tid < 192) bL[tid] = b_in[tid];
  __syncthreads();

  // ---- phase 2: LDS transpose xf[c][i] -> xT32[dt*32+v][c]
  for (int e = tid; e < ROWS * (CC / 4); e += 256) {
    int i = e % ROWS, c4 = e / ROWS;
    int row = (i / VV) * 32 + (i % VV);
    ushort4 h;
    h.x = xf[(c4 * 4 + 0) * XFP + i];
    h.y = xf[(c4 * 4 + 1) * XFP + i];
    h.z = xf[(c4 * 4 + 2) * XFP + i];
    h.w = xf[(c4 * 4 + 3) * XFP + i];
    *(ushort4*)&xT32[row * X3P + c4 * 4] = h;
  }
  __syncthreads();

  // ---- phase 3: QK GEMM D[o=0..191][i'=0..127]; wave mf = 3*wid..3*wid+2
  f32x4 acc[3][8];
  #pragma unroll
  for (int i = 0; i < 3; ++i)
    #pragma unroll
    for (int nf = 0; nf < 8; ++nf) acc[i][nf] = fz();

  #pragma unroll
  for (int ks = 0; ks < 3; ++ks) {
    bf16x8 a[3];
    #pragma unroll
    for (int i = 0; i < 3; ++i)
      a[i] = ldbf8(&wbin[((wid * 3 + i) * 16 + lrow) * 96 + ks * 32 + lk8]);
    #pragma unroll
    for (int nf = 0; nf < 8; ++nf) {
      bf16x8 b = ldbf8(&xT32[(nf * 16 + lrow) * X3P + ks * 32 + lk8]);
      #pragma unroll
      for (int i = 0; i < 3; ++i)
        acc[i][nf] = MFMA16(a[i], b, acc[i][nf]);
    }
  }
  #pragma unroll
  for (int i = 0; i < 3; ++i) {
    int ob = (wid * 3 + i) * 16 + ldr4;
    float4 bb = *(const float4*)&bL[ob];
    #pragma unroll
    for (int nf = 0; nf < 8; ++nf) {
      int col = nf * 16 + lrow;
      ushort4 h;
      h.x = f2b(acc[i][nf][0] + bb.x);
      h.y = f2b(acc[i][nf][1] + bb.y);
      h.z = f2b(acc[i][nf][2] + bb.z);
      h.w = f2b(acc[i][nf][3] + bb.w);
      *(ushort4*)&qk[col * QKP + ob] = h;
    }
  }
  __syncthreads();

  // ---- phase 4: VAL compute (all waves) overlapped with Gram (waves 0-2)
  f32x4 vacc[2][6];
  #pragma unroll
  for (int m = 0; m < 2; ++m)
    #pragma unroll
    for (int of = 0; of < 6; ++of) vacc[m][of] = fz();
  #pragma unroll
  for (int ks = 0; ks < 3; ++ks) {
    bf16x8 bw[6];
    #pragma unroll
    for (int of = 0; of < 6; ++of)
      bw[of] = ldbf8(&wbin[(192 + of * 16 + lrow) * 96 + ks * 32 + lk8]);
    #pragma unroll
    for (int m = 0; m < 2; ++m) {
      bf16x8 a = ldbf8(&xT32[((wid + m * 4) * 16 + lrow) * X3P + ks * 32 + lk8]);
      #pragma unroll
      for (int of = 0; of < 6; ++of)
        vacc[m][of] = MFMA16(a, bw[of], vacc[m][of]);
    }
  }

  if (wid < 3) {
    const int s = wid;
    f32x4 g[2][2];
    g[0][0] = fz(); g[0][1] = fz(); g[1][0] = fz(); g[1][1] = fz();
    #pragma unroll
    for (int dt = 0; dt < TB; ++dt) {
      int r0 = dt * 32;
      bf16x8 a0 = ldbf8(&qk[(r0 + lrow) * QKP + s * 32 + lk8]);
      bf16x8 a1 = ldbf8(&qk[(r0 + 16 + lrow) * QKP + s * 32 + lk8]);
      bf16x8 b0 = ldbf8(&qk[(r0 + lrow) * QKP + 96 + s * 32 + lk8]);
      bf16x8 b1 = ldbf8(&qk[(r0 + 16 + lrow) * QKP + 96 + s * 32 + lk8]);
      g[0][0] = MFMA16(a0, b0, g[0][0]);
      g[0][1] = MFMA16(a0, b1, g[0][1]);
      g[1][0] = MFMA16(a1, b0, g[1][0]);
      g[1][1] = MFMA16(a1, b1, g[1][1]);
    }
    float* pg = partG + ((size_t)tb * (NN * SS) + (n * SS + s)) * (VV * VV);
    #pragma unroll
    for (int mi = 0; mi < 2; ++mi)
      #pragma unroll
      for (int ni = 0; ni < 2; ++ni)
        #pragma unroll
        for (int r = 0; r < 4; ++r) {
          int u = mi * 16 + ldr4 + r, v = ni * 16 + lrow;
          if (u < VV && v < VV) pg[u * VV + v] = g[mi][ni][r];
        }
  }
  __syncthreads();   // Gram's qk reads done -> valL (alias) may be written

  // ---- phase 5: valL[cout][i'] writes (ushort4 along i', aligned)
  float bv[6];
  #pragma unroll
  for (int of = 0; of < 6; ++of) bv[of] = b_in[192 + of * 16 + lrow];
  #pragma unroll
  for (int m = 0; m < 2; ++m) {
    int i0 = (wid + m * 4) * 16 + ldr4;
    #pragma unroll
    for (int of = 0; of < 6; ++of) {
      int cout = of * 16 + lrow;
      ushort4 h;
      h.x = f2b(vacc[m][of][0] + bv[of]);
      h.y = f2b(vacc[m][of][1] + bv[of]);
      h.z = f2b(vacc[m][of][2] + bv[of]);
      h.w = f2b(vacc[m][of][3] + bv[of]);
      *(ushort4*)&valL[cout * 128 + i0] = h;
    }
  }
  __syncthreads();

  // ---- phase 6: coalesced copy-out valL -> val_ws[n][c][t0+t][32]
  for (int e = tid; e < 1536; e += 256) {
    int c4 = e & 3, t = (e >> 2) & 3, cout = e >> 4;
    uint4 w = *(uint4*)&valL[cout * 128 + t * 32 + c4 * 8];
    if (c4 == 3) { w.x &= 0xFFFFu; w.y = 0u; w.z = 0u; w.w = 0u; }  // zero v>=25
    *(uint4*)&val_ws[(((size_t)(n * 96 + cout)) * TT + (t0 + t)) * 32 + c4 * 8] = w;
  }
}

// ---------------------------------------------------------------------------
// k2: reduce partials, tanh + positional gathers -> att bf16 [ns][32][32]
// ---------------------------------------------------------------------------
__global__ __launch_bounds__(256) void k2(
    const float* __restrict__ partG, const float* __restrict__ p_att,
    const float* __restrict__ b_att, unsigned short* __restrict__ att)
{
  const int ns = blockIdx.x;
  for (int e = threadIdx.x; e < 1024; e += 256) {
    int u = e >> 5, v = e & 31;
    float a = 0.f;
    if (u < VV && v < VV) {
      float g = 0.f;
      #pragma unroll 4
      for (int tb = 0; tb < NTB; ++tb)
        g += partG[((size_t)tb * (NN * SS) + ns) * (VV * VV) + u * VV + v];
      a = tanhf(g * (1.0f / 4096.0f))
        + p_att[(size_t)ns * 100 + JP[u] * 10 + JP[v]]
        + b_att[(size_t)ns * 25  + JB[u] * 5  + JB[v]];
    }
    att[(size_t)ns * 1024 + e] = f2b(a);
  }
}

// ---------------------------------------------------------------------------
// k3: per (n, tb): PV (val_ws/att from global) -> yL -> FF -> epilogue.
// ONE barrier. LDS = 23296 (yL) + 19968 (wL) = 43264 B -> 3 blocks/CU.
// ---------------------------------------------------------------------------
__global__ __launch_bounds__(256, 3) void k3(
    const float* __restrict__ x, const unsigned short* __restrict__ val_ws,
    const unsigned short* __restrict__ wbff, const float* __restrict__ scsh,
    const unsigned short* __restrict__ att, float* __restrict__ out)
{
  __shared__ __align__(16) unsigned short yL[112 * YP];   // 23296 B
  __shared__ __align__(16) unsigned short wL[96 * WLP];   // 19968 B

  const int tid  = threadIdx.x;
  const int wid  = tid >> 6, lane = tid & 63;
  const int lrow = lane & 15;
  const int lk8  = (lane >> 4) << 3;
  const int ldr4 = (lane >> 4) << 2;
  const int tb = blockIdx.x & (NTB - 1);
  const int n  = blockIdx.x >> 5;
  const int t0 = tb * TB;
  const int t  = t0 + wid;          // one t per wave

  // stage wff into LDS (independent of PV; covered by the single barrier)
  for (int e = tid; e < 96 * 12; e += 256) {
    int r = e / 12, q = e % 12;
    *(uint4*)&wL[r * WLP + q * 8] = *(const uint4*)&wbff[(size_t)r * 96 + q * 8];
  }

  // ---- PV: D[cm][u] per s ; A = val_ws rows c, B = att rows u (both global)
  const unsigned short* attn = att + (size_t)n * SS * 1024;
  f32x4 pacc[3][2][2];
  #pragma unroll
  for (int s = 0; s < 3; ++s)
    #pragma unroll
    for (int mi = 0; mi < 2; ++mi)
      #pragma unroll
      for (int uf = 0; uf < 2; ++uf) pacc[s][mi][uf] = fz();

  #pragma unroll
  for (int s = 0; s < 3; ++s) {
    bf16x8 av[2], bu[2];
    #pragma unroll
    for (int mi = 0; mi < 2; ++mi) {
      int c = s * 32 + mi * 16 + lrow;
      av[mi] = ldbf8(&val_ws[(((size_t)(n * 96 + c)) * TT + t) * 32 + lk8]);
    }
    #pragma unroll
    for (int uf = 0; uf < 2; ++uf)
      bu[uf] = ldbf8(&attn[s * 1024 + (uf * 16 + lrow) * 32 + lk8]);
    #pragma unroll
    for (int mi = 0; mi < 2; ++mi)
      #pragma unroll
      for (int uf = 0; uf < 2; ++uf)
        pacc[s][mi][uf] = MFMA16(av[mi], bu[uf], pacc[s][mi][uf]);
  }

  // yL[dt*25+u][c] ushort4 writes
  #pragma unroll
  for (int s = 0; s < 3; ++s)
    #pragma unroll
    for (int mi = 0; mi < 2; ++mi)
      #pragma unroll
      for (int uf = 0; uf < 2; ++uf) {
        int u = uf * 16 + lrow;
        if (u < VV) {
          int c0 = s * 32 + mi * 16 + ldr4;
          ushort4 h;
          h.x = f2b(pacc[s][mi][uf][0]);
          h.y = f2b(pacc[s][mi][uf][1]);
          h.z = f2b(pacc[s][mi][uf][2]);
          h.w = f2b(pacc[s][mi][uf][3]);
          *(ushort4*)&yL[(wid * VV + u) * YP + c0] = h;
        }
      }
  __syncthreads();

  // ---- FF: D[o][i] ; A = wL rows o, B = yL rows i ; epilogue fused
  #pragma unroll
  for (int rep = 0; rep < 2; ++rep) {
    int nf = wid + rep * 4;
    if (nf < 7) {
      f32x4 facc[6];
      #pragma unroll
      for (int of = 0; of < 6; ++of) facc[of] = fz();
      #pragma unroll
      for (int ks = 0; ks < 3; ++ks) {
        bf16x8 by = ldbf8(&yL[(nf * 16 + lrow) * YP + ks * 32 + lk8]);
        #pragma unroll
        for (int of = 0; of < 6; ++of) {
          bf16x8 aw = ldbf8(&wL[(of * 16 + lrow) * WLP + ks * 32 + lk8]);
          facc[of] = MFMA16(aw, by, facc[of]);
        }
      }
      int i = nf * 16 + lrow;
      if (i < ROWS) {
        size_t base = (size_t)n * CC * (TT * VV) + (size_t)t0 * VV + i;
        #pragma unroll
        for (int of = 0; of < 6; ++of) {
          int o0 = of * 16 + ldr4;
          float4 sc = *(const float4*)&scsh[o0];
          float4 sh = *(const float4*)&scsh[96 + o0];
          const float* scp = (const float*)&sc;
          const float* shp = (const float*)&sh;
          #pragma unroll
          for (int r = 0; r < 4; ++r) {
            size_t idx = base + (size_t)(o0 + r) * (TT * VV);
            float z = facc[of][r] * scp[r] + shp[r] + x[idx];
            out[idx] = (z >= 0.f) ? z : 0.1f * z;
          }
        }
      }
    }
  }
}

// ---------------------------------------------------------------------------
extern "C" void kernel_launch(void* const* d_in, const int* in_sizes, int n_in,
                              void* d_out, int out_size, void* d_ws, size_t ws_size,
                              hipStream_t stream)
{
  const float* x     = (const float*)d_in[0];
  const float* p_att = (const float*)d_in[1];
  const float* b_att = (const float*)d_in[2];
  const float* w_in  = (const float*)d_in[3];
  const float* b_in  = (const float*)d_in[4];
  const float* w_ff  = (const float*)d_in[5];
  const float* b_ff  = (const float*)d_in[6];
  const float* gam   = (const float*)d_in[7];
  const float* bet   = (const float*)d_in[8];
  const float* mea   = (const float*)d_in[9];
  const float* var   = (const float*)d_in[10];
  float* out = (float*)d_out;

  char* ws = (char*)d_ws;
  unsigned short* wbin = (unsigned short*)ws;              // 55296 B @0
  unsigned short* wbff = wbin + 288 * 96;                  // 18432 B
  unsigned short* attw = wbff + 96 * 96;                   // 393216 B
  float* scsh  = (float*)(ws + 466944);                    // 768 B
  float* partG = (float*)(ws + 467712);                    // 15,360,000 B
  unsigned short* val_ws = (unsigned short*)(ws + 15827712); // 50,331,648 B

  k0<<<108, 256, 0, stream>>>(w_in, w_ff, b_ff, gam, bet, mea, var,
                              wbin, wbff, scsh);
  k1<<<NN * NTB, 256, 0, stream>>>(x, wbin, b_in, partG, val_ws);
  k2<<<NN * SS, 256, 0, stream>>>(partG, p_att, b_att, attw);
  k3<<<NN * NTB, 256, 0, stream>>>(x, val_ws, wbff, scsh, attw, out);
}

// Round 9
// 120.637 us; speedup vs baseline: 1.0851x; 1.0851x over previous
//
#include <hip/hip_runtime.h>
#include <cmath>

#define NN 64
#define CC 96
#define TT 128
#define VV 25
#define SS 3
#define TB 4
#define NTB (TT/TB)          /* 32 */
#define ROWS (TB*VV)         /* 100 */

#define XFP 104              /* xf [c][i-compact] staging pitch */
#define X3P 104              /* xT32 row pitch (128 rows = dt*32+v) */
#define QKP 200              /* qk row pitch (128 rows = i') */
#define YP  104              /* yL row pitch */
#define WLP 104              /* wL row pitch */

typedef __attribute__((ext_vector_type(8))) __bf16 bf16x8;
typedef __attribute__((ext_vector_type(4))) float f32x4;

#define MFMA16(a,b,c) __builtin_amdgcn_mfma_f32_16x16x32_bf16((a),(b),(c),0,0,0)

__constant__ int JP[25] = {0,0,1,1,2,2,2,3,4,4,4,5,6,6,7,7,8,8,9,9,0,3,3,5,5};
__constant__ int JB[25] = {4,4,4,4,0,0,0,0,1,1,1,1,2,2,2,2,3,3,3,3,4,0,0,1,1};

__device__ inline unsigned short f2b(float f) {
  unsigned int u = __float_as_uint(f);
  u += 0x7fffu + ((u >> 16) & 1u);
  return (unsigned short)(u >> 16);
}
__device__ inline bf16x8 ldbf8(const unsigned short* p) {
  union { uint4 u; bf16x8 b; } z;
  z.u = *(const uint4*)p;
  return z.b;
}
__device__ inline f32x4 fz() {
  f32x4 z; z[0] = 0.f; z[1] = 0.f; z[2] = 0.f; z[3] = 0.f; return z;
}

// ---------------------------------------------------------------------------
// k0: weights -> bf16 in ws; BN scale/shift precompute
// ---------------------------------------------------------------------------
__global__ __launch_bounds__(256) void k0(
    const float* __restrict__ w_in, const float* __restrict__ w_ff,
    const float* __restrict__ b_ff, const float* __restrict__ gam,
    const float* __restrict__ bet, const float* __restrict__ mea,
    const float* __restrict__ var,
    unsigned short* __restrict__ wbin, unsigned short* __restrict__ wbff,
    float* __restrict__ scsh)
{
  int i = blockIdx.x * 256 + threadIdx.x;
  if (i < 288 * 96) wbin[i] = f2b(w_in[i]);
  if (i < 96 * 96)  wbff[i] = f2b(w_ff[i]);
  if (i < 96) {
    float sc = gam[i] * rsqrtf(var[i] + 1e-5f);
    scsh[i]      = sc;
    scsh[96 + i] = (b_ff[i] - mea[i]) * sc + bet[i];
  }
}

// ---------------------------------------------------------------------------
// k1: per (n, tb): stage/transpose -> QK GEMM -> { Gram partials ; VAL GEMM
// with RAW fragment-order dump to val_ws (no LDS round-trip, no extra
// barriers) }.  4 phases, 3 barriers.
// val_ws layout per block: frag entry e = of*8 + F (F = i'/16), 64 lanes x
// 4 bf16:  val_ws[blk*12288 + e*256 + lane*4 + r]  holds
//   cout = of*16 + (lane&15),  i' = F*16 + (lane>>4)*4 + r.
// ---------------------------------------------------------------------------
__global__ __launch_bounds__(256, 2) void k1(
    const float* __restrict__ x, const unsigned short* __restrict__ wbin,
    const float* __restrict__ b_in, float* __restrict__ partG,
    unsigned short* __restrict__ val_ws)
{
  __shared__ __align__(16) unsigned short xT32[128 * X3P];  // 26624 B
  __shared__ __align__(16) unsigned short qk[128 * QKP];    // 51200 B
  __shared__ float bL[192];
  unsigned short* xf = qk;   // staging alias (9984 u16), dead after phase 2

  const int tid  = threadIdx.x;
  const int wid  = tid >> 6, lane = tid & 63;
  const int lrow = lane & 15;
  const int lk8  = (lane >> 4) << 3;
  const int ldr4 = (lane >> 4) << 2;
  const int tb = blockIdx.x & (NTB - 1);
  const int n  = blockIdx.x >> 5;
  const int t0 = tb * TB;

  // ---- phase 1: coalesced x load -> xf[c][i-compact]; zero xT32 pad rows
  const float* xb = x + (size_t)n * CC * TT * VV + (size_t)t0 * VV;
  for (int e = tid; e < CC * (ROWS / 4); e += 256) {
    int i4 = e % (ROWS / 4), c = e / (ROWS / 4);
    float4 v = *(const float4*)&xb[(size_t)c * (TT * VV) + i4 * 4];
    ushort4 h;
    h.x = f2b(v.x); h.y = f2b(v.y); h.z = f2b(v.z); h.w = f2b(v.w);
    *(ushort4*)&xf[c * XFP + i4 * 4] = h;
  }
  for (int e = tid; e < 28 * 13; e += 256) {
    int pr = e / 13, q = e % 13;
    int row = (pr / 7) * 32 + 25 + (pr % 7);
    uint4 z; z.x = 0u; z.y = 0u; z.z = 0u; z.w = 0u;
    *(uint4*)&xT32[row * X3P + q * 8] = z;
  }
  if (tid < 192) bL[tid] = b_in[tid];
  __syncthreads();

  // ---- phase 2: LDS transpose xf[c][i] -> xT32[dt*32+v][c]
  for (int e = tid; e < ROWS * (CC / 4); e += 256) {
    int i = e % ROWS, c4 = e / ROWS;
    int row = (i / VV) * 32 + (i % VV);
    ushort4 h;
    h.x = xf[(c4 * 4 + 0) * XFP + i];
    h.y = xf[(c4 * 4 + 1) * XFP + i];
    h.z = xf[(c4 * 4 + 2) * XFP + i];
    h.w = xf[(c4 * 4 + 3) * XFP + i];
    *(ushort4*)&xT32[row * X3P + c4 * 4] = h;
  }
  __syncthreads();

  // ---- phase 3: QK GEMM D[o=0..191][i'=0..127]; wave mf = 3*wid..3*wid+2
  f32x4 acc[3][8];
  #pragma unroll
  for (int i = 0; i < 3; ++i)
    #pragma unroll
    for (int nf = 0; nf < 8; ++nf) acc[i][nf] = fz();

  #pragma unroll
  for (int ks = 0; ks < 3; ++ks) {
    bf16x8 a[3];
    #pragma unroll
    for (int i = 0; i < 3; ++i)
      a[i] = ldbf8(&wbin[((wid * 3 + i) * 16 + lrow) * 96 + ks * 32 + lk8]);
    #pragma unroll
    for (int nf = 0; nf < 8; ++nf) {
      bf16x8 b = ldbf8(&xT32[(nf * 16 + lrow) * X3P + ks * 32 + lk8]);
      #pragma unroll
      for (int i = 0; i < 3; ++i)
        acc[i][nf] = MFMA16(a[i], b, acc[i][nf]);
    }
  }
  #pragma unroll
  for (int i = 0; i < 3; ++i) {
    int ob = (wid * 3 + i) * 16 + ldr4;
    float4 bb = *(const float4*)&bL[ob];
    #pragma unroll
    for (int nf = 0; nf < 8; ++nf) {
      int col = nf * 16 + lrow;
      ushort4 h;
      h.x = f2b(acc[i][nf][0] + bb.x);
      h.y = f2b(acc[i][nf][1] + bb.y);
      h.z = f2b(acc[i][nf][2] + bb.z);
      h.w = f2b(acc[i][nf][3] + bb.w);
      *(ushort4*)&qk[col * QKP + ob] = h;
    }
  }
  __syncthreads();

  // ---- phase 4: VAL GEMM + raw dump (all waves)  ||  Gram (waves 0-2)
  f32x4 vacc[2][6];
  #pragma unroll
  for (int m = 0; m < 2; ++m)
    #pragma unroll
    for (int of = 0; of < 6; ++of) vacc[m][of] = fz();
  #pragma unroll
  for (int ks = 0; ks < 3; ++ks) {
    bf16x8 bw[6];
    #pragma unroll
    for (int of = 0; of < 6; ++of)
      bw[of] = ldbf8(&wbin[(192 + of * 16 + lrow) * 96 + ks * 32 + lk8]);
    #pragma unroll
    for (int m = 0; m < 2; ++m) {
      bf16x8 a = ldbf8(&xT32[((wid + m * 4) * 16 + lrow) * X3P + ks * 32 + lk8]);
      #pragma unroll
      for (int of = 0; of < 6; ++of)
        vacc[m][of] = MFMA16(a, bw[of], vacc[m][of]);
    }
  }
  // fragment-order dump: per (m,of) one 8B store, wave-contiguous 512B
  {
    float bv[6];
    #pragma unroll
    for (int of = 0; of < 6; ++of) bv[of] = bL[0] * 0.f + b_in[192 + of * 16 + lrow];
    unsigned short* vdst = val_ws + (size_t)(n * NTB + tb) * 12288;
    #pragma unroll
    for (int m = 0; m < 2; ++m) {
      int F = wid + m * 4;
      #pragma unroll
      for (int of = 0; of < 6; ++of) {
        ushort4 h;
        h.x = f2b(vacc[m][of][0] + bv[of]);
        h.y = f2b(vacc[m][of][1] + bv[of]);
        h.z = f2b(vacc[m][of][2] + bv[of]);
        h.w = f2b(vacc[m][of][3] + bv[of]);
        *(ushort4*)&vdst[((of * 8 + F) * 64 + lane) * 4] = h;
      }
    }
  }

  if (wid < 3) {
    const int s = wid;
    f32x4 g[2][2];
    g[0][0] = fz(); g[0][1] = fz(); g[1][0] = fz(); g[1][1] = fz();
    #pragma unroll
    for (int dt = 0; dt < TB; ++dt) {
      int r0 = dt * 32;
      bf16x8 a0 = ldbf8(&qk[(r0 + lrow) * QKP + s * 32 + lk8]);
      bf16x8 a1 = ldbf8(&qk[(r0 + 16 + lrow) * QKP + s * 32 + lk8]);
      bf16x8 b0 = ldbf8(&qk[(r0 + lrow) * QKP + 96 + s * 32 + lk8]);
      bf16x8 b1 = ldbf8(&qk[(r0 + 16 + lrow) * QKP + 96 + s * 32 + lk8]);
      g[0][0] = MFMA16(a0, b0, g[0][0]);
      g[0][1] = MFMA16(a0, b1, g[0][1]);
      g[1][0] = MFMA16(a1, b0, g[1][0]);
      g[1][1] = MFMA16(a1, b1, g[1][1]);
    }
    float* pg = partG + ((size_t)tb * (NN * SS) + (n * SS + s)) * (VV * VV);
    #pragma unroll
    for (int mi = 0; mi < 2; ++mi)
      #pragma unroll
      for (int ni = 0; ni < 2; ++ni)
        #pragma unroll
        for (int r = 0; r < 4; ++r) {
          int u = mi * 16 + ldr4 + r, v = ni * 16 + lrow;
          if (u < VV && v < VV) pg[u * VV + v] = g[mi][ni][r];
        }
  }
}

// ---------------------------------------------------------------------------
// k2: reduce partials, tanh + positional gathers -> att bf16 [ns][32][32]
// (att columns v>=25 are ZERO -- k3's PV relies on this to mask val pads)
// ---------------------------------------------------------------------------
__global__ __launch_bounds__(256) void k2(
    const float* __restrict__ partG, const float* __restrict__ p_att,
    const float* __restrict__ b_att, unsigned short* __restrict__ att)
{
  const int ns = blockIdx.x;
  for (int e = threadIdx.x; e < 1024; e += 256) {
    int u = e >> 5, v = e & 31;
    float a = 0.f;
    if (u < VV && v < VV) {
      float g = 0.f;
      #pragma unroll 4
      for (int tb = 0; tb < NTB; ++tb)
        g += partG[((size_t)tb * (NN * SS) + ns) * (VV * VV) + u * VV + v];
      a = tanhf(g * (1.0f / 4096.0f))
        + p_att[(size_t)ns * 100 + JP[u] * 10 + JP[v]]
        + b_att[(size_t)ns * 25  + JB[u] * 5  + JB[v]];
    }
    att[(size_t)ns * 1024 + e] = f2b(a);
  }
}

// ---------------------------------------------------------------------------
// k3: per (n, tb): PV (val_ws fragment-dump + att from global) -> yL -> FF.
// ONE barrier. LDS = 23296 (yL) + 19968 (wL) = 43264 B -> 3 blocks/CU.
// ---------------------------------------------------------------------------
__global__ __launch_bounds__(256, 3) void k3(
    const float* __restrict__ x, const unsigned short* __restrict__ val_ws,
    const unsigned short* __restrict__ wbff, const float* __restrict__ scsh,
    const unsigned short* __restrict__ att, float* __restrict__ out)
{
  __shared__ __align__(16) unsigned short yL[112 * YP];   // 23296 B
  __shared__ __align__(16) unsigned short wL[96 * WLP];   // 19968 B

  const int tid  = threadIdx.x;
  const int wid  = tid >> 6, lane = tid & 63;
  const int lrow = lane & 15;
  const int hi   = lane >> 4;
  const int lk8  = hi << 3;
  const int ldr4 = hi << 2;
  const int tb = blockIdx.x & (NTB - 1);
  const int n  = blockIdx.x >> 5;
  const int t0 = tb * TB;

  // stage wff into LDS (independent of PV; covered by the single barrier)
  for (int e = tid; e < 96 * 12; e += 256) {
    int r = e / 12, q = e % 12;
    *(uint4*)&wL[r * WLP + q * 8] = *(const uint4*)&wbff[(size_t)r * 96 + q * 8];
  }

  // ---- PV: D[cm][u] per s ; A = val frag-dump (global), B = att rows u
  const unsigned short* attn = att + (size_t)n * SS * 1024;
  const unsigned short* vsrc = val_ws + (size_t)(n * NTB + tb) * 12288;
  const int F = wid * 2 + (hi >> 1);
  const int cb = ((hi & 1) * 2) * 16 + lrow;   // chunk-0 lane index

  f32x4 pacc[3][2][2];
  #pragma unroll
  for (int s = 0; s < 3; ++s)
    #pragma unroll
    for (int mi = 0; mi < 2; ++mi)
      #pragma unroll
      for (int uf = 0; uf < 2; ++uf) pacc[s][mi][uf] = fz();

  #pragma unroll
  for (int s = 0; s < 3; ++s) {
    bf16x8 av[2], bu[2];
    #pragma unroll
    for (int mi = 0; mi < 2; ++mi) {
      int of = s * 2 + mi;
      const unsigned short* p = &vsrc[((of * 8 + F) * 64 + cb) * 4];
      union { uint4 u; bf16x8 b; } z;
      uint2 c0 = *(const uint2*)p;
      uint2 c1 = *(const uint2*)(p + 64);      // +16 lanes * 4 u16
      z.u.x = c0.x; z.u.y = c0.y; z.u.z = c1.x; z.u.w = c1.y;
      av[mi] = z.b;
    }
    #pragma unroll
    for (int uf = 0; uf < 2; ++uf)
      bu[uf] = ldbf8(&attn[s * 1024 + (uf * 16 + lrow) * 32 + lk8]);
    #pragma unroll
    for (int mi = 0; mi < 2; ++mi)
      #pragma unroll
      for (int uf = 0; uf < 2; ++uf)
        pacc[s][mi][uf] = MFMA16(av[mi], bu[uf], pacc[s][mi][uf]);
  }

  // yL[dt*25+u][c] ushort4 writes (dt = wid)
  #pragma unroll
  for (int s = 0; s < 3; ++s)
    #pragma unroll
    for (int mi = 0; mi < 2; ++mi)
      #pragma unroll
      for (int uf = 0; uf < 2; ++uf) {
        int u = uf * 16 + lrow;
        if (u < VV) {
          int c0 = s * 32 + mi * 16 + ldr4;
          ushort4 h;
          h.x = f2b(pacc[s][mi][uf][0]);
          h.y = f2b(pacc[s][mi][uf][1]);
          h.z = f2b(pacc[s][mi][uf][2]);
          h.w = f2b(pacc[s][mi][uf][3]);
          *(ushort4*)&yL[(wid * VV + u) * YP + c0] = h;
        }
      }
  __syncthreads();

  // ---- FF: D[o][i] ; A = wL rows o, B = yL rows i ; epilogue fused
  #pragma unroll
  for (int rep = 0; rep < 2; ++rep) {
    int nf = wid + rep * 4;
    if (nf < 7) {
      f32x4 facc[6];
      #pragma unroll
      for (int of = 0; of < 6; ++of) facc[of] = fz();
      #pragma unroll
      for (int ks = 0; ks < 3; ++ks) {
        bf16x8 by = ldbf8(&yL[(nf * 16 + lrow) * YP + ks * 32 + lk8]);
        #pragma unroll
        for (int of = 0; of < 6; ++of) {
          bf16x8 aw = ldbf8(&wL[(of * 16 + lrow) * WLP + ks * 32 + lk8]);
          facc[of] = MFMA16(aw, by, facc[of]);
        }
      }
      int i = nf * 16 + lrow;
      if (i < ROWS) {
        size_t base = (size_t)n * CC * (TT * VV) + (size_t)t0 * VV + i;
        #pragma unroll
        for (int of = 0; of < 6; ++of) {
          int o0 = of * 16 + ldr4;
          float4 sc = *(const float4*)&scsh[o0];
          float4 sh = *(const float4*)&scsh[96 + o0];
          const float* scp = (const float*)&sc;
          const float* shp = (const float*)&sh;
          #pragma unroll
          for (int r = 0; r < 4; ++r) {
            size_t idx = base + (size_t)(o0 + r) * (TT * VV);
            float z = facc[of][r] * scp[r] + shp[r] + x[idx];
            out[idx] = (z >= 0.f) ? z : 0.1f * z;
          }
        }
      }
    }
  }
}

// ---------------------------------------------------------------------------
extern "C" void kernel_launch(void* const* d_in, const int* in_sizes, int n_in,
                              void* d_out, int out_size, void* d_ws, size_t ws_size,
                              hipStream_t stream)
{
  const float* x     = (const float*)d_in[0];
  const float* p_att = (const float*)d_in[1];
  const float* b_att = (const float*)d_in[2];
  const float* w_in  = (const float*)d_in[3];
  const float* b_in  = (const float*)d_in[4];
  const float* w_ff  = (const float*)d_in[5];
  const float* b_ff  = (const float*)d_in[6];
  const float* gam   = (const float*)d_in[7];
  const float* bet   = (const float*)d_in[8];
  const float* mea   = (const float*)d_in[9];
  const float* var   = (const float*)d_in[10];
  float* out = (float*)d_out;

  char* ws = (char*)d_ws;
  unsigned short* wbin = (unsigned short*)ws;              // 55296 B @0
  unsigned short* wbff = wbin + 288 * 96;                  // 18432 B
  unsigned short* attw = wbff + 96 * 96;                   // 393216 B
  float* scsh  = (float*)(ws + 466944);                    // 768 B
  float* partG = (float*)(ws + 467712);                    // 15,360,000 B
  unsigned short* val_ws = (unsigned short*)(ws + 15827712); // 50,331,648 B

  k0<<<108, 256, 0, stream>>>(w_in, w_ff, b_ff, gam, bet, mea, var,
                              wbin, wbff, scsh);
  k1<<<NN * NTB, 256, 0, stream>>>(x, wbin, b_in, partG, val_ws);
  k2<<<NN * SS, 256, 0, stream>>>(partG, p_att, b_att, attw);
  k3<<<NN * NTB, 256, 0, stream>>>(x, val_ws, wbff, scsh, attw, out);
}